// Round 4
// baseline (54.790 us; speedup 1.0000x reference)
//
#include <hip/hip_runtime.h>
#include <cmath>

#define BATCH 8192
#define ACCUMD 256

__device__ __forceinline__ float crelu(float x) {
    float c = fminf(fmaxf(x, -1.0f), 0.9921875f);   // clamp [-1, 127/128]
    return fmaf(0.1f, x - c, c);                    // leak outside the clamp
}

__device__ __forceinline__ void f4add(float4& a, const float4& v) {
    a.x += v.x; a.y += v.y; a.z += v.z; a.w += v.w;
}

__global__ __launch_bounds__(256, 8) void nnue_kernel(
    const int* __restrict__ indices,      // [B*32]
    const int* __restrict__ which_model,  // [B]
    const int* __restrict__ lengths,      // [B]
    const float* __restrict__ embed,      // [F][256]
    const float* __restrict__ main_bias,  // [256]
    const float* __restrict__ W1,         // [16][16][256]
    const float* __restrict__ b1,         // [16][16]
    const float* __restrict__ W2,         // [16][32][16]
    const float* __restrict__ b2,         // [16][32]
    const float* __restrict__ W3,         // [16][1][32]
    const float* __restrict__ b3,         // [16][1]
    float* __restrict__ out)              // [B]
{
    const int w    = threadIdx.x >> 6;    // wave id 0..3 (independent workers)
    const int lane = threadIdx.x & 63;
    const int b    = blockIdx.x * 4 + w;  // batch element owned by this wave

    __shared__ float emb_s[4][ACCUMD];    // per-wave scratch
    __shared__ float h1_s[4][16];

    const float4* embed4 = reinterpret_cast<const float4*>(embed);
    const int* idx = indices + b * 32;    // wave-uniform -> scalar loads

    // ---- Gather-sum of 32 rows: 8-deep rotating pipeline (lean VGPR) ----
    float4 va[8];
    #pragma unroll
    for (int l = 0; l < 8; ++l) va[l] = embed4[(long)idx[l] * 64 + lane];
    float4 acc = make_float4(0.f, 0.f, 0.f, 0.f);
    #pragma unroll
    for (int r = 1; r < 4; ++r) {
        #pragma unroll
        for (int l = 0; l < 8; ++l) {
            float4 nv = embed4[(long)idx[8 * r + l] * 64 + lane];  // issue replacement
            f4add(acc, va[l]);                                     // consume oldest
            va[l] = nv;
        }
    }
    #pragma unroll
    for (int l = 0; l < 8; ++l) f4add(acc, va[l]);

    // ---- Bias, psqt (pre-activation dim 0, lane 0), crelu -> LDS ----
    const float4* mb4 = reinterpret_cast<const float4*>(main_bias);
    float4 tot = acc;
    f4add(tot, mb4[lane]);
    const float psqt = tot.x;             // valid in lane 0 only
    float4 ev;
    ev.x = crelu(tot.x); ev.y = crelu(tot.y); ev.z = crelu(tot.z); ev.w = crelu(tot.w);
    *reinterpret_cast<float4*>(&emb_s[w][4 * lane]) = ev;
    __builtin_amdgcn_wave_barrier();      // wave-local LDS ordering only

    const int e = which_model[b] + (lengths[b] / 17) * 4;   // uniform scalar loads

    // ---- Layer 1: 256 -> 16; 4 lanes per output neuron ----
    {
        const int o = lane >> 2;          // 0..15
        const int j = lane & 3;           // 0..3
        const float4* w1q = reinterpret_cast<const float4*>(W1 + ((e * 16 + o) << 8));
        float p = 0.f;
        #pragma unroll
        for (int k = 0; k < 16; ++k) {
            float4 x = *reinterpret_cast<const float4*>(&emb_s[w][(4 * k + j) * 4]);
            float4 wv = w1q[4 * k + j];
            p = fmaf(x.x, wv.x, fmaf(x.y, wv.y, fmaf(x.z, wv.z, fmaf(x.w, wv.w, p))));
        }
        p += __shfl_xor(p, 1);
        p += __shfl_xor(p, 2);            // all 4 lanes of the group hold the sum
        if (j == 0) h1_s[w][o] = crelu(p + b1[e * 16 + o]);
    }
    __builtin_amdgcn_wave_barrier();

    // ---- Layers 2+3 fused in lanes 0..31: 16 -> 32 -> 1 ----
    if (lane < 32) {
        const float4* h14 = reinterpret_cast<const float4*>(h1_s[w]);
        const float4* w24 = reinterpret_cast<const float4*>(W2 + (e * 32 + lane) * 16);
        float p = b2[e * 32 + lane];
        #pragma unroll
        for (int k = 0; k < 4; ++k) {
            float4 h = h14[k]; float4 wv = w24[k];
            p = fmaf(h.x, wv.x, fmaf(h.y, wv.y, fmaf(h.z, wv.z, fmaf(h.w, wv.w, p))));
        }
        float q = crelu(p) * W3[e * 32 + lane];
        #pragma unroll
        for (int m = 16; m >= 1; m >>= 1) q += __shfl_xor(q, m, 32);
        if (lane == 0) out[b] = tanhf(q + b3[e] + psqt);
    }
}

extern "C" void kernel_launch(void* const* d_in, const int* in_sizes, int n_in,
                              void* d_out, int out_size, void* d_ws, size_t ws_size,
                              hipStream_t stream) {
    const int*   indices     = (const int*)d_in[0];
    // d_in[1] = offsets: always arange(B)*32, unused
    const int*   which_model = (const int*)d_in[2];
    const int*   lengths     = (const int*)d_in[3];
    const float* embed       = (const float*)d_in[4];
    const float* main_bias   = (const float*)d_in[5];
    const float* W1          = (const float*)d_in[6];
    const float* b1          = (const float*)d_in[7];
    const float* W2          = (const float*)d_in[8];
    const float* b2          = (const float*)d_in[9];
    const float* W3          = (const float*)d_in[10];
    const float* b3          = (const float*)d_in[11];
    float* out = (float*)d_out;

    nnue_kernel<<<BATCH / 4, 256, 0, stream>>>(indices, which_model, lengths,
                                               embed, main_bias, W1, b1, W2, b2, W3, b3,
                                               out);
}

// Round 5
// 43.476 us; speedup vs baseline: 1.2602x; 1.2602x over previous
//
#include <hip/hip_runtime.h>
#include <cmath>

#define BATCH 8192
#define ACCUMD 256

__device__ __forceinline__ float crelu(float x) {
    float c = fminf(fmaxf(x, -1.0f), 0.9921875f);   // clamp [-1, 127/128]
    return fmaf(0.1f, x - c, c);                    // leak outside the clamp
}

__device__ __forceinline__ void f4add(float4& a, const float4& v) {
    a.x += v.x; a.y += v.y; a.z += v.z; a.w += v.w;
}

__global__ __launch_bounds__(256) void nnue_kernel(
    const int* __restrict__ indices,      // [B*32]
    const int* __restrict__ which_model,  // [B]
    const int* __restrict__ lengths,      // [B]
    const float* __restrict__ embed,      // [F][256]
    const float* __restrict__ main_bias,  // [256]
    const float* __restrict__ W1,         // [16][16][256]
    const float* __restrict__ b1,         // [16][16]
    const float* __restrict__ W2,         // [16][32][16]
    const float* __restrict__ b2,         // [16][32]
    const float* __restrict__ W3,         // [16][1][32]
    const float* __restrict__ b3,         // [16][1]
    float* __restrict__ out)              // [B]
{
    const int w    = threadIdx.x >> 6;    // wave id 0..3 (independent workers)
    const int lane = threadIdx.x & 63;
    const int b    = blockIdx.x * 4 + w;  // batch element owned by this wave

    __shared__ float emb_s[4][ACCUMD];    // per-wave scratch, no cross-wave sharing
    __shared__ float h1_s[4][16];

    const float4* embed4 = reinterpret_cast<const float4*>(embed);
    const int* idx = indices + b * 32;    // wave-uniform -> scalar loads

    // ---- Gather-sum of 32 rows, 16-deep double-buffered load pipeline ----
    // (16 float4 buffers = 64 VGPRs of in-flight data; this is the MLP depth
    //  that R2->R3 proved worth +20%; the 8-deep "lean" variant of R4 regressed)
    float4 acc = make_float4(0.f, 0.f, 0.f, 0.f);
    float4 va[8], vb[8];
    #pragma unroll
    for (int l = 0; l < 8; ++l) va[l] = embed4[(long)idx[l]      * 64 + lane];
    #pragma unroll
    for (int l = 0; l < 8; ++l) vb[l] = embed4[(long)idx[8 + l]  * 64 + lane];
    #pragma unroll
    for (int l = 0; l < 8; ++l) { f4add(acc, va[l]); va[l] = embed4[(long)idx[16 + l] * 64 + lane]; }
    #pragma unroll
    for (int l = 0; l < 8; ++l) { f4add(acc, vb[l]); vb[l] = embed4[(long)idx[24 + l] * 64 + lane]; }
    #pragma unroll
    for (int l = 0; l < 8; ++l) f4add(acc, va[l]);
    #pragma unroll
    for (int l = 0; l < 8; ++l) f4add(acc, vb[l]);

    // ---- Bias, psqt (pre-activation dim 0, lives in lane 0), crelu -> LDS ----
    const float4* mb4 = reinterpret_cast<const float4*>(main_bias);
    float4 tot = acc;
    f4add(tot, mb4[lane]);
    const float psqt = tot.x;             // valid in lane 0 only
    float4 ev;
    ev.x = crelu(tot.x); ev.y = crelu(tot.y); ev.z = crelu(tot.z); ev.w = crelu(tot.w);
    *reinterpret_cast<float4*>(&emb_s[w][4 * lane]) = ev;
    __builtin_amdgcn_wave_barrier();      // wave-local LDS ordering only

    const int e = which_model[b] + (lengths[b] / 17) * 4;   // uniform scalar loads

    // ---- Layer 1: 256 -> 16; 4 lanes per output neuron ----
    {
        const int o = lane >> 2;          // 0..15
        const int j = lane & 3;           // 0..3
        const float4* w1q = reinterpret_cast<const float4*>(W1 + ((e * 16 + o) << 8));
        float p = 0.f;
        #pragma unroll
        for (int k = 0; k < 16; ++k) {
            float4 x = *reinterpret_cast<const float4*>(&emb_s[w][(4 * k + j) * 4]);
            float4 wv = w1q[4 * k + j];
            p = fmaf(x.x, wv.x, fmaf(x.y, wv.y, fmaf(x.z, wv.z, fmaf(x.w, wv.w, p))));
        }
        p += __shfl_xor(p, 1);
        p += __shfl_xor(p, 2);            // all 4 lanes of the group now hold the sum
        if (j == 0) h1_s[w][o] = crelu(p + b1[e * 16 + o]);
    }
    __builtin_amdgcn_wave_barrier();

    // ---- Layers 2+3 fused in lanes 0..31: 16 -> 32 -> 1 ----
    if (lane < 32) {
        const float4* h14 = reinterpret_cast<const float4*>(h1_s[w]);
        const float4* w24 = reinterpret_cast<const float4*>(W2 + (e * 32 + lane) * 16);
        float p = b2[e * 32 + lane];
        #pragma unroll
        for (int k = 0; k < 4; ++k) {
            float4 h = h14[k]; float4 wv = w24[k];
            p = fmaf(h.x, wv.x, fmaf(h.y, wv.y, fmaf(h.z, wv.z, fmaf(h.w, wv.w, p))));
        }
        float q = crelu(p) * W3[e * 32 + lane];
        #pragma unroll
        for (int m = 16; m >= 1; m >>= 1) q += __shfl_xor(q, m, 32);
        if (lane == 0) out[b] = tanhf(q + b3[e] + psqt);
    }
}

extern "C" void kernel_launch(void* const* d_in, const int* in_sizes, int n_in,
                              void* d_out, int out_size, void* d_ws, size_t ws_size,
                              hipStream_t stream) {
    const int*   indices     = (const int*)d_in[0];
    // d_in[1] = offsets: always arange(B)*32, unused
    const int*   which_model = (const int*)d_in[2];
    const int*   lengths     = (const int*)d_in[3];
    const float* embed       = (const float*)d_in[4];
    const float* main_bias   = (const float*)d_in[5];
    const float* W1          = (const float*)d_in[6];
    const float* b1          = (const float*)d_in[7];
    const float* W2          = (const float*)d_in[8];
    const float* b2          = (const float*)d_in[9];
    const float* W3          = (const float*)d_in[10];
    const float* b3          = (const float*)d_in[11];
    float* out = (float*)d_out;

    nnue_kernel<<<BATCH / 4, 256, 0, stream>>>(indices, which_model, lengths,
                                               embed, main_bias, W1, b1, W2, b2, W3, b3,
                                               out);
}